// Round 1
// baseline (171.705 us; speedup 1.0000x reference)
//
#include <hip/hip_runtime.h>
#include <math.h>

#define NN     4096
#define NB     256            // blocks; co-residency by capacity (validated r4-r8)
#define TPB    1024           // 16 waves per block
#define WPB    16             // nodes (waves) per block
#define CAP    128            // neighbor slots per node (deg incl self ~42, max ~67)
#define GAMMA  0.99f
#define EPSF   1.1920929e-07f // np.finfo(np.float32).eps
#define KSTEPS 10
#define REP    4              // replicas per node value, each on its OWN 64B LLC line
#define LSTR   8              // u64 elements per 64B line

// ---------------------------------------------------------------------------
// r9: barrier-free per-edge DATAFLOW.
// Rocprof r8: VALUBusy 8%, HBM 8.6% -> latency-bound. ~40 of 52 us were the 10
// grid barriers (arrival drain + detect RT + release RT + 256-block straggler
// max, ~4 us/step) while the actual exchange is 2x8B gathers/lane.
// Replace bulk sync with tagged values: one 8B relaxed agent atomic packs
// (float u, int step_tag). Tag+value in ONE word => no cross-address ordering
// needed at all (weaker assumption than the validated r4-r8 visibility chain).
// Consumer spins until tag == t (exact match).
//   poison-safe : ws poison 0xAAAAAAAA as int != any tag in 0..9.
//   no overrun  : adjacency is SYMMETRIC (max(a,aT)+I). j overwrites tag t
//                 (with t+2, other parity plane holds t+1) only after j
//                 consumed all its neighbors' t+1 values, in particular i's,
//                 which i publishes only after consuming j's t. Hence a poller
//                 waiting for t can never observe t+2 -> no deadlock, no lost
//                 update. Parity double-buffer keeps odd/even tags separate.
//   line sharing: r6 lesson - pollers sharing an LLC line serialize ~12ns each.
//                 Every (node,replica) entry gets an exclusive 64B line, REP=4
//                 replicas, consumer picks replica g&3 => ~deg/4 ~ 10 pollers
//                 per line, drain ~0.13 us instead of 0.5.
// Per-neighbor constants (p_j, dinv_j) are gathered ONCE into registers after a
// sign-poll (dinv = sqrt(1/(deg+eps)) > 0 always; poison float is negative), so
// the steady-state step moves only the tagged 8B scalar per neighbor.
// Liveness: all 256 blocks resident by capacity (16 waves, ~8.5KB LDS, ~30
// VGPR -> >=2 blocks/CU capacity on 256 CUs) - same launch shape validated
// r4-r8 with absmax 0.0 on every replay.
// ---------------------------------------------------------------------------

__device__ __forceinline__ unsigned long long pk2(float lo, float hi) {
    return ((unsigned long long)__float_as_uint(hi) << 32) |
            (unsigned long long)__float_as_uint(lo);
}
__device__ __forceinline__ float lo_f(unsigned long long z) {
    return __uint_as_float((unsigned int)z);
}
__device__ __forceinline__ float hi_f(unsigned long long z) {
    return __uint_as_float((unsigned int)(z >> 32));
}
__device__ __forceinline__ unsigned long long pkVT(float v, int tag) {
    return ((unsigned long long)(unsigned int)tag << 32) |
            (unsigned long long)__float_as_uint(v);
}
__device__ __forceinline__ int tag_of(unsigned long long z) {
    return (int)(unsigned int)(z >> 32);
}

__global__ void __launch_bounds__(TPB) gvin_flow(
    const float* __restrict__ adj,  const float* __restrict__ x,
    const float* __restrict__ comms,const float* __restrict__ mask,
    const float* __restrict__ Wr,   const float* __restrict__ br,
    const float* __restrict__ We,   const float* __restrict__ be,
    const float* __restrict__ w_emb,const float* __restrict__ b_emb,
    const float* __restrict__ Wa,   const float* __restrict__ ba,
    unsigned long long* PD, unsigned long long* U0, unsigned long long* U1,
    float* __restrict__ out)
{
    __shared__ int nbr[WPB][CAP];               // 8 KB
    __shared__ int lcnt[WPB];
    const int wave = threadIdx.x >> 6;
    const int lane = threadIdx.x & 63;
    const int g = (int)blockIdx.x * WPB + wave;

    if (lane == 0) { lcnt[wave] = 1; nbr[wave][0] = g; }   // self-loop (a_norm = adj+I)

    // ---- Phase 1: adj row scan -> LDS neighbor list (byte-identical to the
    // validated r6 scan; HBM/L3 streaming floor ~8-10 us) ----
    const float4* rowp = (const float4*)(adj + (size_t)g * NN);
#pragma unroll 4
    for (int it = 0; it < 16; ++it) {
        const float4 v = rowp[lane + it * 64];            // coalesced 16B/lane
        const int b4 = (lane + it * 64) * 4;
        if (v.x != 0.0f) { int sl = atomicAdd(&lcnt[wave], 1); if (sl < CAP) nbr[wave][sl] = b4;     }
        if (v.y != 0.0f) { int sl = atomicAdd(&lcnt[wave], 1); if (sl < CAP) nbr[wave][sl] = b4 + 1; }
        if (v.z != 0.0f) { int sl = atomicAdd(&lcnt[wave], 1); if (sl < CAP) nbr[wave][sl] = b4 + 2; }
        if (v.w != 0.0f) { int sl = atomicAdd(&lcnt[wave], 1); if (sl < CAP) nbr[wave][sl] = b4 + 3; }
    }

    // ---- per-node scalars: r = xc@Wr + br ; s = (xc@We + be)@w_emb ----
    float pr = 0.0f, ps = 0.0f;
    if (lane < 32) {
        const float xc = (lane < 16) ? x[g * 16 + lane] : comms[g * 16 + (lane - 16)];
        float we = 0.0f;
#pragma unroll
        for (int c = 0; c < 8; ++c) we += We[lane * 8 + c] * w_emb[c];
        pr = xc * Wr[lane];
        ps = xc * we;
    } else if (lane == 32) {
#pragma unroll
        for (int c = 0; c < 8; ++c) ps += be[c] * w_emb[c];
        pr = br[0];
    }
#pragma unroll
    for (int off = 32; off; off >>= 1) { pr += __shfl_xor(pr, off); ps += __shfl_xor(ps, off); }
    const float r = pr, s = ps;

    const int   deg  = lcnt[wave];
    const int   cl   = deg < CAP ? deg : CAP;
    const float dinv = sqrtf(1.0f / ((float)deg + EPSF));
    const float p    = dinv * (s + b_emb[0]);

    // ---- publish constants (p,dinv) and u0 = r (tag 0), REP exclusive lines ----
    if (lane < REP) {
        const size_t line = ((size_t)g * REP + lane) * LSTR;
        __hip_atomic_store(PD + line, pk2(p, dinv),
                           __ATOMIC_RELAXED, __HIP_MEMORY_SCOPE_AGENT);
        __hip_atomic_store(U0 + line, pkVT(r, 0),
                           __ATOMIC_RELAXED, __HIP_MEMORY_SCOPE_AGENT);
    }

    // hoist neighbor indices to registers: steps touch no LDS at all
    const bool val0 = lane < cl;
    const bool val1 = 64 + lane < cl;                 // deg max ~67 => <=2 chunks
    const int  j0   = val0 ? nbr[wave][lane] : g;
    const int  j1   = val1 ? nbr[wave][64 + lane] : g;
    const int  rep  = g & (REP - 1);                  // consumer's replica pick
    const size_t e0 = ((size_t)j0 * REP + rep) * LSTR;
    const size_t e1 = ((size_t)j1 * REP + rep) * LSTR;

    float wa[8], bb[8];
#pragma unroll
    for (int c = 0; c < 8; ++c) { wa[c] = Wa[c]; bb[c] = ba[c]; }

    // ---- one-time gather of neighbor constants (p_j, dinv_j): sign-poll.
    // dinv>0 genuinely; poison 0xAAAAAAAA is a negative float -> keeps polling.
    float p0 = 0.0f, d0 = 0.0f, p1 = 0.0f, d1 = 0.0f;
    {
        bool n0 = val0, n1 = val1;
        while (__any(n0 | n1)) {
            if (n0) {
                const unsigned long long z = __hip_atomic_load(
                    PD + e0, __ATOMIC_RELAXED, __HIP_MEMORY_SCOPE_AGENT);
                const float dv = hi_f(z);
                if (dv > 0.0f) { p0 = lo_f(z); d0 = dv; n0 = false; }
            }
            if (n1) {
                const unsigned long long z = __hip_atomic_load(
                    PD + e1, __ATOMIC_RELAXED, __HIP_MEMORY_SCOPE_AGENT);
                const float dv = hi_f(z);
                if (dv > 0.0f) { p1 = lo_f(z); d1 = dv; n1 = false; }
            }
            if (__any(n0 | n1)) __builtin_amdgcn_s_sleep(1);
        }
    }

    // ---- Phase 2: 10 VI steps, pure dataflow (no barrier anywhere) ----
    float v = 0.0f;
    for (int t = 0; t < KSTEPS; ++t) {
        unsigned long long* Uin  = (t & 1) ? U1 : U0;
        unsigned long long* Uout = (t & 1) ? U0 : U1;
        float a1 = 0.0f, a2 = 0.0f;                   // S1 = sum p_j u_j, S2 = sum dinv_j u_j
        bool n0 = val0, n1 = val1;
        while (__any(n0 | n1)) {
            if (n0) {
                const unsigned long long z = __hip_atomic_load(
                    Uin + e0, __ATOMIC_RELAXED, __HIP_MEMORY_SCOPE_AGENT);
                if (tag_of(z) == t) {
                    const float u = lo_f(z);
                    a1 = fmaf(p0, u, a1); a2 = fmaf(d0, u, a2); n0 = false;
                }
            }
            if (n1) {
                const unsigned long long z = __hip_atomic_load(
                    Uin + e1, __ATOMIC_RELAXED, __HIP_MEMORY_SCOPE_AGENT);
                if (tag_of(z) == t) {
                    const float u = lo_f(z);
                    a1 = fmaf(p1, u, a1); a2 = fmaf(d1, u, a2); n1 = false;
                }
            }
            if (__any(n0 | n1)) __builtin_amdgcn_s_sleep(1);
        }
#pragma unroll
        for (int off = 32; off; off >>= 1) { a1 += __shfl_xor(a1, off); a2 += __shfl_xor(a2, off); }
        const float k3v = dinv * (a1 - s * a2);
        v = fmaf(k3v, wa[0], bb[0]);
#pragma unroll
        for (int c = 1; c < 8; ++c) v = fmaxf(v, fmaf(k3v, wa[c], bb[c]));
        // publish u_{t+1} BEFORE the next poll (publish-then-poll order is the
        // deadlock-freedom requirement); u_10 is never consumed -> skip.
        if (t < KSTEPS - 1 && lane < REP) {
            const float u = r + GAMMA * v;
            __hip_atomic_store(Uout + ((size_t)g * REP + lane) * LSTR, pkVT(u, t + 1),
                               __ATOMIC_RELAXED, __HIP_MEMORY_SCOPE_AGENT);
        }
    }

    if (lane == 0) out[g] = v + (mask[g] == 0.0f ? -INFINITY : 0.0f);
}

extern "C" void kernel_launch(void* const* d_in, const int* in_sizes, int n_in,
                              void* d_out, int out_size, void* d_ws, size_t ws_size,
                              hipStream_t stream) {
    const float* x     = (const float*)d_in[0];
    const float* comms = (const float*)d_in[1];
    const float* adj   = (const float*)d_in[2];
    const float* mask  = (const float*)d_in[3];
    const float* Wr    = (const float*)d_in[4];
    const float* br    = (const float*)d_in[5];
    const float* We    = (const float*)d_in[6];
    const float* be    = (const float*)d_in[7];
    const float* w_emb = (const float*)d_in[8];
    const float* b_emb = (const float*)d_in[9];
    const float* Wa    = (const float*)d_in[10];
    const float* ba    = (const float*)d_in[11];
    // d_in[12] = k (fixed at 10, hardcoded)

    // ws: three planes of NN*REP exclusive 64B lines (1 MB each, 3 MB total)
    char* ws = (char*)d_ws;
    const size_t PLANE = (size_t)NN * REP * 64;
    unsigned long long* PD = (unsigned long long*)(ws);
    unsigned long long* U0 = (unsigned long long*)(ws + PLANE);
    unsigned long long* U1 = (unsigned long long*)(ws + 2 * PLANE);
    float* out = (float*)d_out;

    // PLAIN launch: co-residency by capacity (16 waves of 32/CU, ~30 VGPR,
    // ~8.5 KB LDS of 160 KB -> >=2 blocks/CU capacity; all 256 blocks resident
    // at launch). Same shape validated rounds 4-8: absmax 0.0 on every replay.
    gvin_flow<<<dim3(NB), dim3(TPB), 0, stream>>>(
        adj, x, comms, mask, Wr, br, We, be, w_emb, b_emb, Wa, ba,
        PD, U0, U1, out);
}

// Round 2
// 161.083 us; speedup vs baseline: 1.0659x; 1.0659x over previous
//
#include <hip/hip_runtime.h>
#include <math.h>

#define NN     4096
#define NB     256            // blocks; co-residency by capacity (validated r4-r9)
#define TPB    1024           // 16 waves per block
#define WPB    16             // nodes (waves) per block
#define CAP    128            // neighbor slots per node (deg incl self ~42, max ~67)
#define GAMMA  0.99f
#define EPSF   1.1920929e-07f // np.finfo(np.float32).eps
#define KSTEPS 10
#define PDSTR  8              // u64 elems per 64B line: PD gets an exclusive line/node

// ---------------------------------------------------------------------------
// r10: barrier-free dataflow, BULK-SWEEP edition.
// r9 post-mortem: per-edge scattered polling (172K pollers re-issuing 8B
// agent loads every ~latency) congested the fabric and added +45 MB of real
// HBM fetch; steps ran 5.8 us vs the r8 barrier's 3.9. The tagged-word
// protocol itself validated (absmax 0.0). Fix the ACCESS PATTERN, not the
// protocol: the whole u-plane is 4096 x 8B = 32 KB, so each block COALESCED-
// SWEEPS the full plane into LDS once per step (1024 thr x 4 contiguous 8B
// agent loads), gathers neighbors from LDS, and only the stale subset falls
// back to scattered global re-polls. No grid barrier, no arrival/release
// arrays, no replicas.
// Correctness carried over from r9 (all validated there, absmax 0.0):
//   tagged word : one 8B relaxed agent atomic packs (float u, int step_tag);
//                 tag+value in ONE word => no cross-address ordering needed.
//   poison-safe : ws poison 0xAAAAAAAA as int tag is negative != any t in 0..9;
//                 PD poison has dinv<0 (sign-poll).
//   no overrun  : adjacency is SYMMETRIC (max(a,aT)+I). Plane t&1 is
//                 overwritten (tag t+2) by node j only after j consumed all
//                 neighbors' t+1 words - in particular i's, which i publishes
//                 only after consuming j's t. So a consumer waiting for tag t
//                 never sees t+2; parity double-buffer separates odd/even.
//   liveness    : all 256 blocks resident by capacity (1024 thr, ~41 KB LDS
//                 of 160 KB, ~32 VGPR -> 1 block/CU on 256 CUs). Publish
//                 happens BEFORE the next sweep's polls (publish-then-poll).
// Sweep-vs-stale detail: the LDS copy may contain stale words (sweep raced a
// producer); each wave validates ONLY its own j0/j1 entries and re-polls those
// directly from the LLC - the straggler subset, not the full edge set.
// Diagnostic for this round: FETCH_SIZE should return to ~35 MB (adjacency
// only). If it balloons >100 MB, agent atomics bypass the LLC -> revert.
// ---------------------------------------------------------------------------

union F2U { unsigned long long u; float2 f; };

__device__ __forceinline__ unsigned long long pk2(float lo, float hi) {
    return ((unsigned long long)__float_as_uint(hi) << 32) |
            (unsigned long long)__float_as_uint(lo);
}
__device__ __forceinline__ float lo_f(unsigned long long z) {
    return __uint_as_float((unsigned int)z);
}
__device__ __forceinline__ float hi_f(unsigned long long z) {
    return __uint_as_float((unsigned int)(z >> 32));
}
__device__ __forceinline__ unsigned long long pkVT(float v, int tag) {
    return ((unsigned long long)(unsigned int)tag << 32) |
            (unsigned long long)__float_as_uint(v);
}
__device__ __forceinline__ int tag_of(unsigned long long z) {
    return (int)(unsigned int)(z >> 32);
}

__global__ void __launch_bounds__(TPB) gvin_sweep(
    const float* __restrict__ adj,  const float* __restrict__ x,
    const float* __restrict__ comms,const float* __restrict__ mask,
    const float* __restrict__ Wr,   const float* __restrict__ br,
    const float* __restrict__ We,   const float* __restrict__ be,
    const float* __restrict__ w_emb,const float* __restrict__ b_emb,
    const float* __restrict__ Wa,   const float* __restrict__ ba,
    unsigned long long* PD, unsigned long long* U0, unsigned long long* U1,
    float* __restrict__ out)
{
    __shared__ int nbr[WPB][CAP];               // 8 KB
    __shared__ int lcnt[WPB];
    __shared__ unsigned long long ULDS[NN];     // 32 KB: block-local u-plane copy
    const int wave = threadIdx.x >> 6;
    const int lane = threadIdx.x & 63;
    const int g = (int)blockIdx.x * WPB + wave;

    if (lane == 0) { lcnt[wave] = 1; nbr[wave][0] = g; }   // self-loop (a_norm = adj+I)

    // ---- Phase 1: adj row scan -> LDS neighbor list (byte-identical to the
    // validated r6 scan; HBM/L3 streaming floor ~10-13 us) ----
    const float4* rowp = (const float4*)(adj + (size_t)g * NN);
#pragma unroll 4
    for (int it = 0; it < 16; ++it) {
        const float4 v = rowp[lane + it * 64];            // coalesced 16B/lane
        const int b4 = (lane + it * 64) * 4;
        if (v.x != 0.0f) { int sl = atomicAdd(&lcnt[wave], 1); if (sl < CAP) nbr[wave][sl] = b4;     }
        if (v.y != 0.0f) { int sl = atomicAdd(&lcnt[wave], 1); if (sl < CAP) nbr[wave][sl] = b4 + 1; }
        if (v.z != 0.0f) { int sl = atomicAdd(&lcnt[wave], 1); if (sl < CAP) nbr[wave][sl] = b4 + 2; }
        if (v.w != 0.0f) { int sl = atomicAdd(&lcnt[wave], 1); if (sl < CAP) nbr[wave][sl] = b4 + 3; }
    }

    // ---- per-node scalars: r = xc@Wr + br ; s = (xc@We + be)@w_emb ----
    float pr = 0.0f, ps = 0.0f;
    if (lane < 32) {
        const float xc = (lane < 16) ? x[g * 16 + lane] : comms[g * 16 + (lane - 16)];
        float we = 0.0f;
#pragma unroll
        for (int c = 0; c < 8; ++c) we += We[lane * 8 + c] * w_emb[c];
        pr = xc * Wr[lane];
        ps = xc * we;
    } else if (lane == 32) {
#pragma unroll
        for (int c = 0; c < 8; ++c) ps += be[c] * w_emb[c];
        pr = br[0];
    }
#pragma unroll
    for (int off = 32; off; off >>= 1) { pr += __shfl_xor(pr, off); ps += __shfl_xor(ps, off); }
    const float r = pr, s = ps;

    const int   deg  = lcnt[wave];
    const int   cl   = deg < CAP ? deg : CAP;
    const float dinv = sqrtf(1.0f / ((float)deg + EPSF));
    const float p    = dinv * (s + b_emb[0]);

    // ---- publish PD (exclusive 64B line) and u0 = r with tag 0 -----------
    // publish-before-poll: these land before this wave starts polling others.
    if (lane == 0) {
        __hip_atomic_store(PD + (size_t)g * PDSTR, pk2(p, dinv),
                           __ATOMIC_RELAXED, __HIP_MEMORY_SCOPE_AGENT);
        __hip_atomic_store(U0 + g, pkVT(r, 0),
                           __ATOMIC_RELAXED, __HIP_MEMORY_SCOPE_AGENT);
    }

    // hoist neighbor indices to registers: steps touch nbr[] no more
    const bool val0 = lane < cl;
    const bool val1 = 64 + lane < cl;                 // deg max ~67 => <=2 chunks
    const int  j0   = val0 ? nbr[wave][lane] : g;
    const int  j1   = val1 ? nbr[wave][64 + lane] : g;

    float wa[8], bb[8];
#pragma unroll
    for (int c = 0; c < 8; ++c) { wa[c] = Wa[c]; bb[c] = ba[c]; }

    // ---- one-time gather of neighbor constants (p_j, dinv_j): sign-poll
    // (validated r9). dinv>0 genuinely; poison float is negative -> keep polling.
    float p0 = 0.0f, d0 = 0.0f, p1 = 0.0f, d1 = 0.0f;
    {
        bool n0 = val0, n1 = val1;
        while (__any(n0 | n1)) {
            if (n0) {
                const unsigned long long z = __hip_atomic_load(
                    PD + (size_t)j0 * PDSTR, __ATOMIC_RELAXED, __HIP_MEMORY_SCOPE_AGENT);
                const float dv = hi_f(z);
                if (dv > 0.0f) { p0 = lo_f(z); d0 = dv; n0 = false; }
            }
            if (n1) {
                const unsigned long long z = __hip_atomic_load(
                    PD + (size_t)j1 * PDSTR, __ATOMIC_RELAXED, __HIP_MEMORY_SCOPE_AGENT);
                const float dv = hi_f(z);
                if (dv > 0.0f) { p1 = lo_f(z); d1 = dv; n1 = false; }
            }
            if (__any(n0 | n1)) __builtin_amdgcn_s_sleep(1);
        }
    }

    // ---- Phase 2: 10 VI steps; per step: bulk sweep plane -> LDS, gather
    // from LDS, scattered re-poll only for the stale subset. No barrier. ----
    float v = 0.0f;
    for (int t = 0; t < KSTEPS; ++t) {
        unsigned long long* Uin  = (t & 1) ? U1 : U0;
        unsigned long long* Uout = (t & 1) ? U0 : U1;

        __syncthreads();                          // ULDS free; all publishes issued
#pragma unroll
        for (int w = 0; w < NN / TPB; ++w) {      // 4 coalesced 8B atomic loads/thread
            const int idx = (int)threadIdx.x + (w << 10);
            ULDS[idx] = __hip_atomic_load(Uin + idx, __ATOMIC_RELAXED,
                                          __HIP_MEMORY_SCOPE_AGENT);
        }
        __syncthreads();                          // LDS copy complete

        unsigned long long z0 = ULDS[j0];
        unsigned long long z1 = ULDS[j1];
        bool n0 = val0 && (tag_of(z0) != t);      // validate ONLY needed entries
        bool n1 = val1 && (tag_of(z1) != t);
        while (__any(n0 | n1)) {                  // straggler subset: direct re-poll
            if (n0) {
                z0 = __hip_atomic_load(Uin + j0, __ATOMIC_RELAXED, __HIP_MEMORY_SCOPE_AGENT);
                n0 = (tag_of(z0) != t);
            }
            if (n1) {
                z1 = __hip_atomic_load(Uin + j1, __ATOMIC_RELAXED, __HIP_MEMORY_SCOPE_AGENT);
                n1 = (tag_of(z1) != t);
            }
            if (__any(n0 | n1)) __builtin_amdgcn_s_sleep(1);
        }

        const float u0f = val0 ? lo_f(z0) : 0.0f;
        float a1 = p0 * u0f, a2 = d0 * u0f;       // S1 = sum p_j u_j, S2 = sum dinv_j u_j
        if (val1) { const float u1f = lo_f(z1); a1 = fmaf(p1, u1f, a1); a2 = fmaf(d1, u1f, a2); }
#pragma unroll
        for (int off = 32; off; off >>= 1) { a1 += __shfl_xor(a1, off); a2 += __shfl_xor(a2, off); }
        const float k3v = dinv * (a1 - s * a2);
        v = fmaf(k3v, wa[0], bb[0]);
#pragma unroll
        for (int c = 1; c < 8; ++c) v = fmaxf(v, fmaf(k3v, wa[c], bb[c]));
        // publish u_{t+1} BEFORE the next sweep (publish-then-poll is the
        // deadlock-freedom requirement); u_10 is never consumed -> skip.
        if (t < KSTEPS - 1 && lane == 0) {
            __hip_atomic_store(Uout + g, pkVT(r + GAMMA * v, t + 1),
                               __ATOMIC_RELAXED, __HIP_MEMORY_SCOPE_AGENT);
        }
    }

    if (lane == 0) out[g] = v + (mask[g] == 0.0f ? -INFINITY : 0.0f);
}

extern "C" void kernel_launch(void* const* d_in, const int* in_sizes, int n_in,
                              void* d_out, int out_size, void* d_ws, size_t ws_size,
                              hipStream_t stream) {
    const float* x     = (const float*)d_in[0];
    const float* comms = (const float*)d_in[1];
    const float* adj   = (const float*)d_in[2];
    const float* mask  = (const float*)d_in[3];
    const float* Wr    = (const float*)d_in[4];
    const float* br    = (const float*)d_in[5];
    const float* We    = (const float*)d_in[6];
    const float* be    = (const float*)d_in[7];
    const float* w_emb = (const float*)d_in[8];
    const float* b_emb = (const float*)d_in[9];
    const float* Wa    = (const float*)d_in[10];
    const float* ba    = (const float*)d_in[11];
    // d_in[12] = k (fixed at 10, hardcoded)

    // ws: PD = 4096 exclusive 64B lines (256 KB); U0/U1 = packed 32 KB planes.
    // Total 320 KB (r9 passed with 3 MB -> ws is large enough).
    char* ws = (char*)d_ws;
    unsigned long long* PD = (unsigned long long*)(ws);
    unsigned long long* U0 = (unsigned long long*)(ws + (size_t)NN * 64);
    unsigned long long* U1 = (unsigned long long*)(ws + (size_t)NN * 64 + (size_t)NN * 8);
    float* out = (float*)d_out;

    // PLAIN launch: co-residency by capacity (1024 thr, ~41 KB LDS of 160 KB,
    // ~32 VGPR -> 1 block/CU; all 256 blocks resident at launch). Same shape
    // validated rounds 4-9: absmax 0.0 on every replay.
    gvin_sweep<<<dim3(NB), dim3(TPB), 0, stream>>>(
        adj, x, comms, mask, Wr, br, We, be, w_emb, b_emb, Wa, ba,
        PD, U0, U1, out);
}